// Round 4
// baseline (1728.048 us; speedup 1.0000x reference)
//
#include <hip/hip_runtime.h>

#define NN 100000
#define NE 1600000
#define NADJ 2
#define NLAY 3
#define HD 128
#define NG 1024

#define SCAN_BLOCKS ((NN + 255) / 256)   // 391

__device__ __forceinline__ float f4c(const float4 v, int k) {
    return k == 0 ? v.x : (k == 1 ? v.y : (k == 2 ? v.z : v.w));
}

// C[N x 128] = A[N x 128] @ W[128 x 128] (+bias)(optionally row-scaled)(+relu).
// 32 rows per block. If dscale != null, C[row] *= dscale[row] (fused GCN norm).
__global__ __launch_bounds__(256) void gemm_nk128(
    const float* __restrict__ A, const float* __restrict__ W,
    float* __restrict__ C, const float* __restrict__ bias,
    const float* __restrict__ dscale, int relu)
{
    __shared__ float sW[128 * 128];   // 64 KB
    __shared__ float sA[32 * 128];    // 16 KB, xor-swizzled in float4 units
    const int t = threadIdx.x;
    const int blk = blockIdx.x;

    const float4* Wv = (const float4*)W;
    float4* sWv = (float4*)sW;
    #pragma unroll
    for (int i = 0; i < 16; ++i) sWv[i * 256 + t] = Wv[i * 256 + t];

    const float4* Av = (const float4*)(A + (size_t)blk * 32 * 128);
    float4* sAv = (float4*)sA;
    #pragma unroll
    for (int i = 0; i < 4; ++i) {
        int f = i * 256 + t;
        int row = f >> 5, c4 = f & 31;
        sAv[row * 32 + (c4 ^ (row >> 2))] = Av[f];
    }
    __syncthreads();

    const int rg = t & 7, cg = t >> 3;   // 8 row-groups x 32 col-groups
    float4 acc[4];
    #pragma unroll
    for (int i = 0; i < 4; ++i) acc[i] = make_float4(0.f, 0.f, 0.f, 0.f);

    #pragma unroll 8
    for (int k0 = 0; k0 < 128; k0 += 4) {
        float4 a[4], b[4];
        #pragma unroll
        for (int i = 0; i < 4; ++i)
            a[i] = sAv[(rg * 4 + i) * 32 + ((k0 >> 2) ^ rg)];
        #pragma unroll
        for (int kk = 0; kk < 4; ++kk)
            b[kk] = sWv[(k0 + kk) * 32 + cg];
        #pragma unroll
        for (int kk = 0; kk < 4; ++kk) {
            #pragma unroll
            for (int i = 0; i < 4; ++i) {
                float av = f4c(a[i], kk);
                acc[i].x = fmaf(av, b[kk].x, acc[i].x);
                acc[i].y = fmaf(av, b[kk].y, acc[i].y);
                acc[i].z = fmaf(av, b[kk].z, acc[i].z);
                acc[i].w = fmaf(av, b[kk].w, acc[i].w);
            }
        }
    }

    float4 bb = make_float4(0.f, 0.f, 0.f, 0.f);
    if (bias) bb = ((const float4*)bias)[cg];
    float4* Cv = (float4*)C;
    #pragma unroll
    for (int i = 0; i < 4; ++i) {
        int row = blk * 32 + rg * 4 + i;
        float4 o = acc[i];
        o.x += bb.x; o.y += bb.y; o.z += bb.z; o.w += bb.w;
        if (dscale) {
            float ds = dscale[row];
            o.x *= ds; o.y *= ds; o.z *= ds; o.w *= ds;
        }
        if (relu) {
            o.x = fmaxf(o.x, 0.f); o.y = fmaxf(o.y, 0.f);
            o.z = fmaxf(o.z, 0.f); o.w = fmaxf(o.w, 0.f);
        }
        Cv[(size_t)row * 32 + cg] = o;
    }
}

__global__ void hist_col(const int* __restrict__ col, int* __restrict__ cnt) {
    int e = blockIdx.x * 256 + threadIdx.x;
    if (e < NE) atomicAdd(&cnt[col[e]], 1);
}

// ---- hierarchical scan: cnt -> row_ptr/cursor (exclusive), dis = rsqrt(cnt+1)

__global__ __launch_bounds__(256) void block_sums(
    const int* __restrict__ cnt, int* __restrict__ bsum)
{
    __shared__ int ws[4];
    int i = blockIdx.x * 256 + threadIdx.x;
    int v = (i < NN) ? cnt[i] : 0;
    #pragma unroll
    for (int off = 32; off > 0; off >>= 1) v += __shfl_xor(v, off);
    int wid = threadIdx.x >> 6;
    if ((threadIdx.x & 63) == 0) ws[wid] = v;
    __syncthreads();
    if (threadIdx.x == 0) bsum[blockIdx.x] = ws[0] + ws[1] + ws[2] + ws[3];
}

__global__ __launch_bounds__(512) void scan_bsums(int* __restrict__ bsum)
{
    __shared__ int s[512];
    int t = threadIdx.x;
    int v = (t < SCAN_BLOCKS) ? bsum[t] : 0;
    s[t] = v;
    __syncthreads();
    #pragma unroll
    for (int off = 1; off < 512; off <<= 1) {
        int u = (t >= off) ? s[t - off] : 0;
        __syncthreads();
        s[t] += u;
        __syncthreads();
    }
    if (t < SCAN_BLOCKS) bsum[t] = s[t] - v;   // exclusive
}

__global__ __launch_bounds__(256) void write_rowptr(
    const int* __restrict__ cnt, const int* __restrict__ bsum,
    int* __restrict__ row_ptr, int* __restrict__ cursor,
    float* __restrict__ dis)
{
    __shared__ int s[256];
    int t = threadIdx.x;
    int i = blockIdx.x * 256 + t;
    int v = (i < NN) ? cnt[i] : 0;
    s[t] = v;
    __syncthreads();
    #pragma unroll
    for (int off = 1; off < 256; off <<= 1) {
        int u = (t >= off) ? s[t - off] : 0;
        __syncthreads();
        s[t] += u;
        __syncthreads();
    }
    if (i < NN) {
        int excl = bsum[blockIdx.x] + s[t] - v;
        row_ptr[i] = excl;
        cursor[i] = excl;
        dis[i] = rsqrtf((float)(v + 1));   // +1 self loop
        if (i == NN - 1) row_ptr[NN] = excl + v;
    }
}

// Only csr_src is materialized; edge weight dis[r]*dis[c] is factored into
// the GEMM epilogue (mm = dis .* (h@W)) and the agg epilogue (out *= dis).
__global__ void scatter_edges(
    const int* __restrict__ row, const int* __restrict__ col,
    int* __restrict__ cursor, int* __restrict__ csr_src)
{
    int e = blockIdx.x * 256 + threadIdx.x;
    if (e >= NE) return;
    int r = row[e], c = col[e];
    int p = atomicAdd(&cursor[c], 1);
    csr_src[p] = r;
}

// out[i] = relu( dis[i] * ( mm[i] + sum_e mm[src_e] ) ), one wave per node.
// Predicated UN=16: every edge goes through the wide path (no serial tail),
// 16 independent 512B row-gathers in flight per wave.
__global__ __launch_bounds__(256) void agg_relu(
    const float* __restrict__ mm, const int* __restrict__ row_ptr,
    const int* __restrict__ csr_src,
    const float* __restrict__ dis, float* __restrict__ out)
{
    int node = blockIdx.x * 4 + (threadIdx.x >> 6);
    if (node >= NN) return;
    int lane = threadIdx.x & 63;
    const float2* mv = (const float2*)mm;
    float2 self = mv[(size_t)node * 64 + lane];
    float accx = self.x;
    float accy = self.y;
    int e0 = row_ptr[node], e1 = row_ptr[node + 1];

    #define UN 16
    for (int e = e0; e < e1; e += UN) {
        int   ss[UN];
        float mk[UN];
        #pragma unroll
        for (int u = 0; u < UN; ++u) {
            int idx = e + u;
            ss[u] = csr_src[min(idx, e1 - 1)];   // safe: loop entered => e1 > e0
            mk[u] = (idx < e1) ? 1.f : 0.f;
        }
        float2 vv[UN];
        #pragma unroll
        for (int u = 0; u < UN; ++u)
            vv[u] = mv[(size_t)ss[u] * 64 + lane];
        #pragma unroll
        for (int u = 0; u < UN; ++u) {
            accx = fmaf(mk[u], vv[u].x, accx);
            accy = fmaf(mk[u], vv[u].y, accy);
        }
    }
    #undef UN

    float d = dis[node];
    float2 o;
    o.x = fmaxf(d * accx, 0.f);
    o.y = fmaxf(d * accy, 0.f);
    ((float2*)out)[(size_t)node * 64 + lane] = o;
}

// pooled[batch[n]][aoff + c] += h[n][c], exploiting sorted batch
__global__ __launch_bounds__(128) void pool_add(
    const float* __restrict__ h, const int* __restrict__ batch,
    float* __restrict__ pooled, int aoff)
{
    int c = threadIdx.x;
    int n0 = blockIdx.x * 64;
    int nend = min(n0 + 64, NN);
    int cur = batch[n0];
    float acc = 0.f;
    for (int n = n0; n < nend; ++n) {
        int g = batch[n];
        if (g != cur) {
            atomicAdd(&pooled[(size_t)cur * 256 + aoff + c], acc);
            acc = 0.f;
            cur = g;
        }
        acc += h[(size_t)n * 128 + c];
    }
    atomicAdd(&pooled[(size_t)cur * 256 + aoff + c], acc);
}

// out[g] = relu(pooled[g] @ w1 + b1) @ w2 + b2
__global__ __launch_bounds__(128) void head(
    const float* __restrict__ pooled,
    const float* __restrict__ w1, const float* __restrict__ b1,
    const float* __restrict__ w2, const float* __restrict__ b2,
    float* __restrict__ out)
{
    __shared__ float sp[256];
    __shared__ float sg[128];
    int g = blockIdx.x, t = threadIdx.x;
    sp[t] = pooled[(size_t)g * 256 + t];
    sp[t + 128] = pooled[(size_t)g * 256 + 128 + t];
    __syncthreads();
    float acc = b1[t];
    #pragma unroll 8
    for (int k = 0; k < 256; ++k) acc = fmaf(sp[k], w1[k * 128 + t], acc);
    sg[t] = fmaxf(acc, 0.f) * w2[t];
    __syncthreads();
    for (int s2 = 64; s2 > 0; s2 >>= 1) {
        if (t < s2) sg[t] += sg[t + s2];
        __syncthreads();
    }
    if (t == 0) out[g] = sg[0] + b2[0];
}

extern "C" void kernel_launch(void* const* d_in, const int* in_sizes, int n_in,
                              void* d_out, int out_size, void* d_ws, size_t ws_size,
                              hipStream_t stream) {
    const float* x      = (const float*)d_in[0];
    const int*   ei     = (const int*)d_in[1];
    const int*   batch  = (const int*)d_in[2];
    const float* lin0_w = (const float*)d_in[3];
    const float* lin0_b = (const float*)d_in[4];
    const float* conv_w = (const float*)d_in[5];
    const float* lin1_w = (const float*)d_in[6];
    const float* lin1_b = (const float*)d_in[7];
    const float* lin2_w = (const float*)d_in[8];
    const float* lin2_b = (const float*)d_in[9];
    float* out = (float*)d_out;

    const size_t NB = (size_t)NN * HD;
    float* x0     = (float*)d_ws;
    float* bufA   = x0 + NB;
    float* bufB   = bufA + NB;
    float* pooled = bufB + NB;
    int*   cnt     = (int*)(pooled + (size_t)NG * 256);
    int*   row_ptr = cnt + NN;
    int*   cursor  = row_ptr + NN + 1;
    float* dis     = (float*)(cursor + NN);
    int*   csr_src = (int*)(dis + NN);
    int*   bsum    = csr_src + NE;

    hipMemsetAsync(pooled, 0, (size_t)NG * 256 * sizeof(float), stream);

    // x0 = relu(x @ lin0_w + lin0_b)
    gemm_nk128<<<NN / 32, 256, 0, stream>>>(x, lin0_w, x0, lin0_b, nullptr, 1);

    for (int a = 0; a < NADJ; ++a) {
        const int* row = ei + (size_t)a * 2 * NE;
        const int* col = row + NE;

        hipMemsetAsync(cnt, 0, NN * sizeof(int), stream);
        hist_col<<<(NE + 255) / 256, 256, 0, stream>>>(col, cnt);
        block_sums<<<SCAN_BLOCKS, 256, 0, stream>>>(cnt, bsum);
        scan_bsums<<<1, 512, 0, stream>>>(bsum);
        write_rowptr<<<SCAN_BLOCKS, 256, 0, stream>>>(cnt, bsum, row_ptr,
                                                      cursor, dis);
        scatter_edges<<<(NE + 255) / 256, 256, 0, stream>>>(row, col, cursor,
                                                            csr_src);

        const float* h = x0;
        for (int l = 0; l < NLAY; ++l) {
            const float* W = conv_w + ((size_t)a * NLAY + l) * HD * HD;
            // mm = dis .* (h @ W)
            gemm_nk128<<<NN / 32, 256, 0, stream>>>(h, W, bufA, nullptr, dis, 0);
            agg_relu<<<(NN + 3) / 4, 256, 0, stream>>>(bufA, row_ptr, csr_src,
                                                       dis, bufB);
            h = bufB;
        }
        pool_add<<<(NN + 63) / 64, 128, 0, stream>>>(bufB, batch, pooled, a * HD);
    }

    head<<<NG, 128, 0, stream>>>(pooled, lin1_w, lin1_b, lin2_w, lin2_b, out);
}

// Round 5
// 1285.780 us; speedup vs baseline: 1.3440x; 1.3440x over previous
//
#include <hip/hip_runtime.h>

#define NN 100000
#define NE 1600000
#define NADJ 2
#define NLAY 3
#define HD 128
#define NG 1024

#define SCAN_BLOCKS ((NN + 255) / 256)   // 391

typedef unsigned int uint32;
typedef unsigned short ushort16;

__device__ __forceinline__ float f4c(const float4 v, int k) {
    return k == 0 ? v.x : (k == 1 ? v.y : (k == 2 ? v.z : v.w));
}

__device__ __forceinline__ ushort16 f2bf(float f) {   // RNE pack
    uint32 u = __float_as_uint(f);
    u += 0x7FFFu + ((u >> 16) & 1u);
    return (ushort16)(u >> 16);
}
__device__ __forceinline__ float bflo(uint32 u) { return __uint_as_float(u << 16); }
__device__ __forceinline__ float bfhi(uint32 u) { return __uint_as_float(u & 0xFFFF0000u); }

// C[N x 128] = A[N x 128] @ W[128 x 128] (+bias)(+rowscale)(+relu).
// Output either fp32 (C) or bf16 (Cbf) — exactly one non-null.
__global__ __launch_bounds__(256) void gemm_nk128(
    const float* __restrict__ A, const float* __restrict__ W,
    float* __restrict__ C, ushort16* __restrict__ Cbf,
    const float* __restrict__ bias, const float* __restrict__ dscale, int relu)
{
    __shared__ float sW[128 * 128];   // 64 KB
    __shared__ float sA[32 * 128];    // 16 KB, xor-swizzled in float4 units
    const int t = threadIdx.x;
    const int blk = blockIdx.x;

    const float4* Wv = (const float4*)W;
    float4* sWv = (float4*)sW;
    #pragma unroll
    for (int i = 0; i < 16; ++i) sWv[i * 256 + t] = Wv[i * 256 + t];

    const float4* Av = (const float4*)(A + (size_t)blk * 32 * 128);
    float4* sAv = (float4*)sA;
    #pragma unroll
    for (int i = 0; i < 4; ++i) {
        int f = i * 256 + t;
        int row = f >> 5, c4 = f & 31;
        sAv[row * 32 + (c4 ^ (row >> 2))] = Av[f];
    }
    __syncthreads();

    const int rg = t & 7, cg = t >> 3;   // 8 row-groups x 32 col-groups
    float4 acc[4];
    #pragma unroll
    for (int i = 0; i < 4; ++i) acc[i] = make_float4(0.f, 0.f, 0.f, 0.f);

    #pragma unroll 8
    for (int k0 = 0; k0 < 128; k0 += 4) {
        float4 a[4], b[4];
        #pragma unroll
        for (int i = 0; i < 4; ++i)
            a[i] = sAv[(rg * 4 + i) * 32 + ((k0 >> 2) ^ rg)];
        #pragma unroll
        for (int kk = 0; kk < 4; ++kk)
            b[kk] = sWv[(k0 + kk) * 32 + cg];
        #pragma unroll
        for (int kk = 0; kk < 4; ++kk) {
            #pragma unroll
            for (int i = 0; i < 4; ++i) {
                float av = f4c(a[i], kk);
                acc[i].x = fmaf(av, b[kk].x, acc[i].x);
                acc[i].y = fmaf(av, b[kk].y, acc[i].y);
                acc[i].z = fmaf(av, b[kk].z, acc[i].z);
                acc[i].w = fmaf(av, b[kk].w, acc[i].w);
            }
        }
    }

    float4 bb = make_float4(0.f, 0.f, 0.f, 0.f);
    if (bias) bb = ((const float4*)bias)[cg];
    #pragma unroll
    for (int i = 0; i < 4; ++i) {
        int row = blk * 32 + rg * 4 + i;
        float4 o = acc[i];
        o.x += bb.x; o.y += bb.y; o.z += bb.z; o.w += bb.w;
        if (dscale) {
            float ds = dscale[row];
            o.x *= ds; o.y *= ds; o.z *= ds; o.w *= ds;
        }
        if (relu) {
            o.x = fmaxf(o.x, 0.f); o.y = fmaxf(o.y, 0.f);
            o.z = fmaxf(o.z, 0.f); o.w = fmaxf(o.w, 0.f);
        }
        if (C) {
            ((float4*)C)[(size_t)row * 32 + cg] = o;
        } else {
            ushort16 p0 = f2bf(o.x), p1 = f2bf(o.y), p2 = f2bf(o.z), p3 = f2bf(o.w);
            uint32 lo = (uint32)p0 | ((uint32)p1 << 16);
            uint32 hi = (uint32)p2 | ((uint32)p3 << 16);
            ((uint2*)Cbf)[(size_t)row * 32 + cg] = make_uint2(lo, hi);
        }
    }
}

// histogram of col + per-edge local offset (old count), coalesced write
__global__ void hist_plocal(const int* __restrict__ col,
                            int* __restrict__ cnt, int* __restrict__ p_local) {
    int e = blockIdx.x * 256 + threadIdx.x;
    if (e < NE) p_local[e] = atomicAdd(&cnt[col[e]], 1);
}

// ---- hierarchical scan: cnt -> row_ptr (exclusive), dis = rsqrt(cnt+1)

__global__ __launch_bounds__(256) void block_sums(
    const int* __restrict__ cnt, int* __restrict__ bsum)
{
    __shared__ int ws[4];
    int i = blockIdx.x * 256 + threadIdx.x;
    int v = (i < NN) ? cnt[i] : 0;
    #pragma unroll
    for (int off = 32; off > 0; off >>= 1) v += __shfl_xor(v, off);
    int wid = threadIdx.x >> 6;
    if ((threadIdx.x & 63) == 0) ws[wid] = v;
    __syncthreads();
    if (threadIdx.x == 0) bsum[blockIdx.x] = ws[0] + ws[1] + ws[2] + ws[3];
}

__global__ __launch_bounds__(512) void scan_bsums(int* __restrict__ bsum)
{
    __shared__ int s[512];
    int t = threadIdx.x;
    int v = (t < SCAN_BLOCKS) ? bsum[t] : 0;
    s[t] = v;
    __syncthreads();
    #pragma unroll
    for (int off = 1; off < 512; off <<= 1) {
        int u = (t >= off) ? s[t - off] : 0;
        __syncthreads();
        s[t] += u;
        __syncthreads();
    }
    if (t < SCAN_BLOCKS) bsum[t] = s[t] - v;   // exclusive
}

__global__ __launch_bounds__(256) void write_rowptr(
    const int* __restrict__ cnt, const int* __restrict__ bsum,
    int* __restrict__ row_ptr, float* __restrict__ dis)
{
    __shared__ int s[256];
    int t = threadIdx.x;
    int i = blockIdx.x * 256 + t;
    int v = (i < NN) ? cnt[i] : 0;
    s[t] = v;
    __syncthreads();
    #pragma unroll
    for (int off = 1; off < 256; off <<= 1) {
        int u = (t >= off) ? s[t - off] : 0;
        __syncthreads();
        s[t] += u;
        __syncthreads();
    }
    if (i < NN) {
        int excl = bsum[blockIdx.x] + s[t] - v;
        row_ptr[i] = excl;
        dis[i] = rsqrtf((float)(v + 1));   // +1 self loop
        if (i == NN - 1) row_ptr[NN] = excl + v;
    }
}

// atomic-free scatter: slot = row_ptr[col] + p_local (all coalesced reads)
__global__ void scatter_edges(
    const int* __restrict__ row, const int* __restrict__ col,
    const int* __restrict__ p_local, const int* __restrict__ row_ptr,
    int* __restrict__ csr_src)
{
    int e = blockIdx.x * 256 + threadIdx.x;
    if (e >= NE) return;
    csr_src[row_ptr[col[e]] + p_local[e]] = row[e];
}

// out[i] = relu( dis[i] * ( mm[i] + sum_e mm[src_e] ) ), one wave per node.
// mm is bf16 [NN x 128]; per lane 4B (2 cols). Exact UN=16 main loop +
// one masked tail iteration (tail's clamped dupes are L1 hits).
__global__ __launch_bounds__(256) void agg_relu(
    const ushort16* __restrict__ mm, const int* __restrict__ row_ptr,
    const int* __restrict__ csr_src,
    const float* __restrict__ dis, float* __restrict__ out)
{
    int node = blockIdx.x * 4 + (threadIdx.x >> 6);
    if (node >= NN) return;
    int lane = threadIdx.x & 63;
    const uint32* mv = (const uint32*)mm;
    uint32 self = mv[(size_t)node * 64 + lane];
    float accx = bflo(self);
    float accy = bfhi(self);
    int e0 = row_ptr[node], e1 = row_ptr[node + 1];

    #define UN 16
    int e = e0;
    for (; e + UN <= e1; e += UN) {
        int ss[UN];
        #pragma unroll
        for (int u = 0; u < UN; ++u) ss[u] = csr_src[e + u];
        uint32 vv[UN];
        #pragma unroll
        for (int u = 0; u < UN; ++u)
            vv[u] = mv[(size_t)ss[u] * 64 + lane];
        #pragma unroll
        for (int u = 0; u < UN; ++u) {
            accx += bflo(vv[u]);
            accy += bfhi(vv[u]);
        }
    }
    if (e < e1) {   // masked tail
        int ss[UN];
        float mk[UN];
        #pragma unroll
        for (int u = 0; u < UN; ++u) {
            int idx = e + u;
            ss[u] = csr_src[min(idx, e1 - 1)];
            mk[u] = (idx < e1) ? 1.f : 0.f;
        }
        uint32 vv[UN];
        #pragma unroll
        for (int u = 0; u < UN; ++u)
            vv[u] = mv[(size_t)ss[u] * 64 + lane];
        #pragma unroll
        for (int u = 0; u < UN; ++u) {
            accx = fmaf(mk[u], bflo(vv[u]), accx);
            accy = fmaf(mk[u], bfhi(vv[u]), accy);
        }
    }
    #undef UN

    float d = dis[node];
    float2 o;
    o.x = fmaxf(d * accx, 0.f);
    o.y = fmaxf(d * accy, 0.f);
    ((float2*)out)[(size_t)node * 64 + lane] = o;
}

// pooled[batch[n]][aoff + c] += h[n][c], exploiting sorted batch
__global__ __launch_bounds__(128) void pool_add(
    const float* __restrict__ h, const int* __restrict__ batch,
    float* __restrict__ pooled, int aoff)
{
    int c = threadIdx.x;
    int n0 = blockIdx.x * 64;
    int nend = min(n0 + 64, NN);
    int cur = batch[n0];
    float acc = 0.f;
    for (int n = n0; n < nend; ++n) {
        int g = batch[n];
        if (g != cur) {
            atomicAdd(&pooled[(size_t)cur * 256 + aoff + c], acc);
            acc = 0.f;
            cur = g;
        }
        acc += h[(size_t)n * 128 + c];
    }
    atomicAdd(&pooled[(size_t)cur * 256 + aoff + c], acc);
}

// out[g] = relu(pooled[g] @ w1 + b1) @ w2 + b2
__global__ __launch_bounds__(128) void head(
    const float* __restrict__ pooled,
    const float* __restrict__ w1, const float* __restrict__ b1,
    const float* __restrict__ w2, const float* __restrict__ b2,
    float* __restrict__ out)
{
    __shared__ float sp[256];
    __shared__ float sg[128];
    int g = blockIdx.x, t = threadIdx.x;
    sp[t] = pooled[(size_t)g * 256 + t];
    sp[t + 128] = pooled[(size_t)g * 256 + 128 + t];
    __syncthreads();
    float acc = b1[t];
    #pragma unroll 8
    for (int k = 0; k < 256; ++k) acc = fmaf(sp[k], w1[k * 128 + t], acc);
    sg[t] = fmaxf(acc, 0.f) * w2[t];
    __syncthreads();
    for (int s2 = 64; s2 > 0; s2 >>= 1) {
        if (t < s2) sg[t] += sg[t + s2];
        __syncthreads();
    }
    if (t == 0) out[g] = sg[0] + b2[0];
}

extern "C" void kernel_launch(void* const* d_in, const int* in_sizes, int n_in,
                              void* d_out, int out_size, void* d_ws, size_t ws_size,
                              hipStream_t stream) {
    const float* x      = (const float*)d_in[0];
    const int*   ei     = (const int*)d_in[1];
    const int*   batch  = (const int*)d_in[2];
    const float* lin0_w = (const float*)d_in[3];
    const float* lin0_b = (const float*)d_in[4];
    const float* conv_w = (const float*)d_in[5];
    const float* lin1_w = (const float*)d_in[6];
    const float* lin1_b = (const float*)d_in[7];
    const float* lin2_w = (const float*)d_in[8];
    const float* lin2_b = (const float*)d_in[9];
    float* out = (float*)d_out;

    const size_t NB = (size_t)NN * HD;
    float* x0     = (float*)d_ws;
    float* bufA   = x0 + NB;                   // mm (bf16) lives here; also p_local
    float* bufB   = bufA + NB;
    float* pooled = bufB + NB;
    int*   cnt     = (int*)(pooled + (size_t)NG * 256);
    int*   row_ptr = cnt + NN;
    float* dis     = (float*)(row_ptr + NN + 1);
    int*   csr_src = (int*)(dis + NN);
    int*   bsum    = csr_src + NE;

    ushort16* mm  = (ushort16*)bufA;
    int* p_local  = (int*)bufA;   // dead before first gemm writes mm (sequential stream)

    hipMemsetAsync(pooled, 0, (size_t)NG * 256 * sizeof(float), stream);

    // x0 = relu(x @ lin0_w + lin0_b)  (fp32 out)
    gemm_nk128<<<NN / 32, 256, 0, stream>>>(x, lin0_w, x0, nullptr, lin0_b,
                                            nullptr, 1);

    for (int a = 0; a < NADJ; ++a) {
        const int* row = ei + (size_t)a * 2 * NE;
        const int* col = row + NE;

        hipMemsetAsync(cnt, 0, NN * sizeof(int), stream);
        hist_plocal<<<(NE + 255) / 256, 256, 0, stream>>>(col, cnt, p_local);
        block_sums<<<SCAN_BLOCKS, 256, 0, stream>>>(cnt, bsum);
        scan_bsums<<<1, 512, 0, stream>>>(bsum);
        write_rowptr<<<SCAN_BLOCKS, 256, 0, stream>>>(cnt, bsum, row_ptr, dis);
        scatter_edges<<<(NE + 255) / 256, 256, 0, stream>>>(row, col, p_local,
                                                            row_ptr, csr_src);

        const float* h = x0;
        for (int l = 0; l < NLAY; ++l) {
            const float* W = conv_w + ((size_t)a * NLAY + l) * HD * HD;
            // mm = bf16( dis .* (h @ W) )
            gemm_nk128<<<NN / 32, 256, 0, stream>>>(h, W, nullptr, mm, nullptr,
                                                    dis, 0);
            agg_relu<<<(NN + 3) / 4, 256, 0, stream>>>(mm, row_ptr, csr_src,
                                                       dis, bufB);
            h = bufB;
        }
        pool_add<<<(NN + 63) / 64, 128, 0, stream>>>(bufB, batch, pooled, a * HD);
    }

    head<<<NG, 128, 0, stream>>>(pooled, lin1_w, lin1_b, lin2_w, lin2_b, out);
}

// Round 6
// 837.455 us; speedup vs baseline: 2.0635x; 1.5353x over previous
//
#include <hip/hip_runtime.h>

#define NN 100000
#define NE 1600000
#define NADJ 2
#define NLAY 3
#define HD 128
#define NG 1024

#define SCAN_BLOCKS ((NN + 255) / 256)   // 391

typedef unsigned int uint32;
typedef unsigned short u16;

typedef __attribute__((ext_vector_type(8))) short bfrag8;   // 8 bf16 (4 VGPR)
typedef __attribute__((ext_vector_type(4))) float f32x4;

__device__ __forceinline__ float f4c(const float4 v, int k) {
    return k == 0 ? v.x : (k == 1 ? v.y : (k == 2 ? v.z : v.w));
}

__device__ __forceinline__ u16 f2bf(float f) {   // RNE pack
    uint32 u = __float_as_uint(f);
    u += 0x7FFFu + ((u >> 16) & 1u);
    return (u16)(u >> 16);
}
__device__ __forceinline__ float bflo(uint32 u) { return __uint_as_float(u << 16); }
__device__ __forceinline__ float bfhi(uint32 u) { return __uint_as_float(u & 0xFFFF0000u); }

// ---------------- fp32 VALU GEMM (lin0 only): C/Cbf = relu(A@W + b) ----------
__global__ __launch_bounds__(256) void gemm_nk128(
    const float* __restrict__ A, const float* __restrict__ W,
    float* __restrict__ C, u16* __restrict__ Cbf,
    const float* __restrict__ bias, const float* __restrict__ dscale, int relu)
{
    __shared__ float sW[128 * 128];
    __shared__ float sA[32 * 128];
    const int t = threadIdx.x;
    const int blk = blockIdx.x;

    const float4* Wv = (const float4*)W;
    float4* sWv = (float4*)sW;
    #pragma unroll
    for (int i = 0; i < 16; ++i) sWv[i * 256 + t] = Wv[i * 256 + t];

    const float4* Av = (const float4*)(A + (size_t)blk * 32 * 128);
    float4* sAv = (float4*)sA;
    #pragma unroll
    for (int i = 0; i < 4; ++i) {
        int f = i * 256 + t;
        int row = f >> 5, c4 = f & 31;
        sAv[row * 32 + (c4 ^ (row >> 2))] = Av[f];
    }
    __syncthreads();

    const int rg = t & 7, cg = t >> 3;
    float4 acc[4];
    #pragma unroll
    for (int i = 0; i < 4; ++i) acc[i] = make_float4(0.f, 0.f, 0.f, 0.f);

    #pragma unroll 8
    for (int k0 = 0; k0 < 128; k0 += 4) {
        float4 a[4], b[4];
        #pragma unroll
        for (int i = 0; i < 4; ++i)
            a[i] = sAv[(rg * 4 + i) * 32 + ((k0 >> 2) ^ rg)];
        #pragma unroll
        for (int kk = 0; kk < 4; ++kk)
            b[kk] = sWv[(k0 + kk) * 32 + cg];
        #pragma unroll
        for (int kk = 0; kk < 4; ++kk) {
            #pragma unroll
            for (int i = 0; i < 4; ++i) {
                float av = f4c(a[i], kk);
                acc[i].x = fmaf(av, b[kk].x, acc[i].x);
                acc[i].y = fmaf(av, b[kk].y, acc[i].y);
                acc[i].z = fmaf(av, b[kk].z, acc[i].z);
                acc[i].w = fmaf(av, b[kk].w, acc[i].w);
            }
        }
    }

    float4 bb = make_float4(0.f, 0.f, 0.f, 0.f);
    if (bias) bb = ((const float4*)bias)[cg];
    #pragma unroll
    for (int i = 0; i < 4; ++i) {
        int row = blk * 32 + rg * 4 + i;
        float4 o = acc[i];
        o.x += bb.x; o.y += bb.y; o.z += bb.z; o.w += bb.w;
        if (dscale) {
            float ds = dscale[row];
            o.x *= ds; o.y *= ds; o.z *= ds; o.w *= ds;
        }
        if (relu) {
            o.x = fmaxf(o.x, 0.f); o.y = fmaxf(o.y, 0.f);
            o.z = fmaxf(o.z, 0.f); o.w = fmaxf(o.w, 0.f);
        }
        if (C) {
            ((float4*)C)[(size_t)row * 32 + cg] = o;
        } else {
            uint32 lo = (uint32)f2bf(o.x) | ((uint32)f2bf(o.y) << 16);
            uint32 hi = (uint32)f2bf(o.z) | ((uint32)f2bf(o.w) << 16);
            ((uint2*)Cbf)[(size_t)row * 32 + cg] = make_uint2(lo, hi);
        }
    }
}

// one-time: wt[a,l][n][k] = bf16(conv_w[a,l][k][n])   (6 matrices)
__global__ void wt_prep(const float* __restrict__ conv_w, u16* __restrict__ wt) {
    const float* W = conv_w + (size_t)blockIdx.x * HD * HD;
    u16* o = wt + (size_t)blockIdx.x * HD * HD;
    for (int i = 0; i < 64; ++i) {
        int idx = i * 256 + threadIdx.x;
        int n = idx >> 7, k = idx & 127;
        o[idx] = f2bf(W[k * 128 + n]);
    }
}

// ---------------- MFMA conv GEMM: mm = bf16( dis .* (h @ W) ) ----------------
// h bf16 [NN][128], Wt bf16 [n][k]. 128 rows/block, 4 waves (2x2), K=128.
// LDS 16B slots XOR-swizzled: slot ^= row&15 (T2; <=2-way conflicts = free).
__global__ __launch_bounds__(256) void gemm_mfma_conv(
    const u16* __restrict__ Abf, const u16* __restrict__ Wt,
    u16* __restrict__ mm, const float* __restrict__ dis)
{
    __shared__ u16 sA[128 * 128];
    __shared__ u16 sB[128 * 128];
    const int t = threadIdx.x;
    const int row0 = blockIdx.x * 128;

    #pragma unroll
    for (int i = 0; i < 8; ++i) {
        int f = i * 256 + t;                  // 16B-slot id: row=f>>4, s=f&15
        int r = f >> 4, s = f & 15;
        int gr = min(row0 + r, NN - 1);       // tail clamp
        uint4 v = ((const uint4*)Abf)[(size_t)gr * 16 + s];
        *(uint4*)&sA[(r * 16 + (s ^ (r & 15))) * 8] = v;
    }
    #pragma unroll
    for (int i = 0; i < 8; ++i) {
        int f = i * 256 + t;
        int r = f >> 4, s = f & 15;
        uint4 v = ((const uint4*)Wt)[f];
        *(uint4*)&sB[(r * 16 + (s ^ (r & 15))) * 8] = v;
    }
    __syncthreads();

    const int w = t >> 6, lane = t & 63;
    const int wr = (w >> 1) * 64, wc = (w & 1) * 64;
    const int lr = lane & 15, kg = lane >> 4;

    const f32x4 z = {0.f, 0.f, 0.f, 0.f};
    f32x4 acc[4][4];
    #pragma unroll
    for (int i = 0; i < 4; ++i)
        #pragma unroll
        for (int j = 0; j < 4; ++j) acc[i][j] = z;

    #pragma unroll
    for (int ks = 0; ks < 4; ++ks) {          // K = 4 x 32
        bfrag8 a[4], b[4];
        #pragma unroll
        for (int i = 0; i < 4; ++i) {
            int r = wr + i * 16 + lr;
            int s = (ks * 4 + kg) ^ (r & 15);
            a[i] = *(const bfrag8*)&sA[(r * 16 + s) * 8];
        }
        #pragma unroll
        for (int j = 0; j < 4; ++j) {
            int r = wc + j * 16 + lr;
            int s = (ks * 4 + kg) ^ (r & 15);
            b[j] = *(const bfrag8*)&sB[(r * 16 + s) * 8];
        }
        #pragma unroll
        for (int i = 0; i < 4; ++i)
            #pragma unroll
            for (int j = 0; j < 4; ++j)
                acc[i][j] = __builtin_amdgcn_mfma_f32_16x16x32_bf16(
                    a[i], b[j], acc[i][j], 0, 0, 0);
    }

    // C/D: col = lane&15, row = (lane>>4)*4 + reg   [m89-verified]
    #pragma unroll
    for (int i = 0; i < 4; ++i) {
        #pragma unroll
        for (int r = 0; r < 4; ++r) {
            int grow = row0 + wr + i * 16 + kg * 4 + r;
            if (grow < NN) {
                float ds = dis[grow];
                #pragma unroll
                for (int j = 0; j < 4; ++j) {
                    int gcol = wc + j * 16 + lr;
                    mm[(size_t)grow * 128 + gcol] = f2bf(acc[i][j][r] * ds);
                }
            }
        }
    }
}

// histogram of col + per-edge local offset (old count), coalesced write
__global__ void hist_plocal(const int* __restrict__ col,
                            int* __restrict__ cnt, int* __restrict__ p_local) {
    int e = blockIdx.x * 256 + threadIdx.x;
    if (e < NE) p_local[e] = atomicAdd(&cnt[col[e]], 1);
}

// ---- hierarchical scan: cnt -> row_ptr (exclusive), dis = rsqrt(cnt+1)

__global__ __launch_bounds__(256) void block_sums(
    const int* __restrict__ cnt, int* __restrict__ bsum)
{
    __shared__ int ws[4];
    int i = blockIdx.x * 256 + threadIdx.x;
    int v = (i < NN) ? cnt[i] : 0;
    #pragma unroll
    for (int off = 32; off > 0; off >>= 1) v += __shfl_xor(v, off);
    int wid = threadIdx.x >> 6;
    if ((threadIdx.x & 63) == 0) ws[wid] = v;
    __syncthreads();
    if (threadIdx.x == 0) bsum[blockIdx.x] = ws[0] + ws[1] + ws[2] + ws[3];
}

__global__ __launch_bounds__(512) void scan_bsums(int* __restrict__ bsum)
{
    __shared__ int s[512];
    int t = threadIdx.x;
    int v = (t < SCAN_BLOCKS) ? bsum[t] : 0;
    s[t] = v;
    __syncthreads();
    #pragma unroll
    for (int off = 1; off < 512; off <<= 1) {
        int u = (t >= off) ? s[t - off] : 0;
        __syncthreads();
        s[t] += u;
        __syncthreads();
    }
    if (t < SCAN_BLOCKS) bsum[t] = s[t] - v;   // exclusive
}

__global__ __launch_bounds__(256) void write_rowptr(
    const int* __restrict__ cnt, const int* __restrict__ bsum,
    int* __restrict__ row_ptr, float* __restrict__ dis)
{
    __shared__ int s[256];
    int t = threadIdx.x;
    int i = blockIdx.x * 256 + t;
    int v = (i < NN) ? cnt[i] : 0;
    s[t] = v;
    __syncthreads();
    #pragma unroll
    for (int off = 1; off < 256; off <<= 1) {
        int u = (t >= off) ? s[t - off] : 0;
        __syncthreads();
        s[t] += u;
        __syncthreads();
    }
    if (i < NN) {
        int excl = bsum[blockIdx.x] + s[t] - v;
        row_ptr[i] = excl;
        dis[i] = rsqrtf((float)(v + 1));   // +1 self loop
        if (i == NN - 1) row_ptr[NN] = excl + v;
    }
}

// atomic-free scatter: slot = row_ptr[col] + p_local
__global__ void scatter_edges(
    const int* __restrict__ row, const int* __restrict__ col,
    const int* __restrict__ p_local, const int* __restrict__ row_ptr,
    int* __restrict__ csr_src)
{
    int e = blockIdx.x * 256 + threadIdx.x;
    if (e >= NE) return;
    csr_src[row_ptr[col[e]] + p_local[e]] = row[e];
}

// out[i] = bf16( relu( dis[i] * ( mm[i] + sum_e mm[src_e] ) ) ), one wave/node.
__global__ __launch_bounds__(256) void agg_relu(
    const u16* __restrict__ mm, const int* __restrict__ row_ptr,
    const int* __restrict__ csr_src,
    const float* __restrict__ dis, u16* __restrict__ out)
{
    int node = blockIdx.x * 4 + (threadIdx.x >> 6);
    if (node >= NN) return;
    int lane = threadIdx.x & 63;
    const uint32* mv = (const uint32*)mm;
    uint32 self = mv[(size_t)node * 64 + lane];
    float accx = bflo(self);
    float accy = bfhi(self);
    int e0 = row_ptr[node], e1 = row_ptr[node + 1];

    #define UN 16
    int e = e0;
    for (; e + UN <= e1; e += UN) {
        int ss[UN];
        #pragma unroll
        for (int u = 0; u < UN; ++u) ss[u] = csr_src[e + u];
        uint32 vv[UN];
        #pragma unroll
        for (int u = 0; u < UN; ++u)
            vv[u] = mv[(size_t)ss[u] * 64 + lane];
        #pragma unroll
        for (int u = 0; u < UN; ++u) {
            accx += bflo(vv[u]);
            accy += bfhi(vv[u]);
        }
    }
    if (e < e1) {   // masked tail
        int ss[UN];
        float mk[UN];
        #pragma unroll
        for (int u = 0; u < UN; ++u) {
            int idx = e + u;
            ss[u] = csr_src[min(idx, e1 - 1)];
            mk[u] = (idx < e1) ? 1.f : 0.f;
        }
        uint32 vv[UN];
        #pragma unroll
        for (int u = 0; u < UN; ++u)
            vv[u] = mv[(size_t)ss[u] * 64 + lane];
        #pragma unroll
        for (int u = 0; u < UN; ++u) {
            accx = fmaf(mk[u], bflo(vv[u]), accx);
            accy = fmaf(mk[u], bfhi(vv[u]), accy);
        }
    }
    #undef UN

    float d = dis[node];
    uint32 po = (uint32)f2bf(fmaxf(d * accx, 0.f))
              | ((uint32)f2bf(fmaxf(d * accy, 0.f)) << 16);
    ((uint32*)out)[(size_t)node * 64 + lane] = po;
}

// pooled[batch[n]][aoff + c] += h[n][c]   (h bf16, sorted batch)
__global__ __launch_bounds__(128) void pool_add(
    const u16* __restrict__ h, const int* __restrict__ batch,
    float* __restrict__ pooled, int aoff)
{
    int c = threadIdx.x;
    int n0 = blockIdx.x * 64;
    int nend = min(n0 + 64, NN);
    int cur = batch[n0];
    float acc = 0.f;
    for (int n = n0; n < nend; ++n) {
        int g = batch[n];
        if (g != cur) {
            atomicAdd(&pooled[(size_t)cur * 256 + aoff + c], acc);
            acc = 0.f;
            cur = g;
        }
        acc += __uint_as_float((uint32)h[(size_t)n * 128 + c] << 16);
    }
    atomicAdd(&pooled[(size_t)cur * 256 + aoff + c], acc);
}

// out[g] = relu(pooled[g] @ w1 + b1) @ w2 + b2
__global__ __launch_bounds__(128) void head(
    const float* __restrict__ pooled,
    const float* __restrict__ w1, const float* __restrict__ b1,
    const float* __restrict__ w2, const float* __restrict__ b2,
    float* __restrict__ out)
{
    __shared__ float sp[256];
    __shared__ float sg[128];
    int g = blockIdx.x, t = threadIdx.x;
    sp[t] = pooled[(size_t)g * 256 + t];
    sp[t + 128] = pooled[(size_t)g * 256 + 128 + t];
    __syncthreads();
    float acc = b1[t];
    #pragma unroll 8
    for (int k = 0; k < 256; ++k) acc = fmaf(sp[k], w1[k * 128 + t], acc);
    sg[t] = fmaxf(acc, 0.f) * w2[t];
    __syncthreads();
    for (int s2 = 64; s2 > 0; s2 >>= 1) {
        if (t < s2) sg[t] += sg[t + s2];
        __syncthreads();
    }
    if (t == 0) out[g] = sg[0] + b2[0];
}

extern "C" void kernel_launch(void* const* d_in, const int* in_sizes, int n_in,
                              void* d_out, int out_size, void* d_ws, size_t ws_size,
                              hipStream_t stream) {
    const float* x      = (const float*)d_in[0];
    const int*   ei     = (const int*)d_in[1];
    const int*   batch  = (const int*)d_in[2];
    const float* lin0_w = (const float*)d_in[3];
    const float* lin0_b = (const float*)d_in[4];
    const float* conv_w = (const float*)d_in[5];
    const float* lin1_w = (const float*)d_in[6];
    const float* lin1_b = (const float*)d_in[7];
    const float* lin2_w = (const float*)d_in[8];
    const float* lin2_b = (const float*)d_in[9];
    float* out = (float*)d_out;

    const size_t NB = (size_t)NN * HD;
    float* x0f    = (float*)d_ws;              // region reused: x0 bf16
    float* bufA   = x0f + NB;                  // mm (bf16); also p_local
    float* bufB   = bufA + NB;                 // h (bf16)
    float* pooled = bufB + NB;
    int*   cnt     = (int*)(pooled + (size_t)NG * 256);
    int*   row_ptr = cnt + NN;
    float* dis     = (float*)(row_ptr + NN + 1);
    int*   csr_src = (int*)(dis + NN);
    int*   bsum    = csr_src + NE;
    u16*   wt      = (u16*)(bsum + 512);       // 6 x 128 x 128 bf16 = 192 KB

    u16* x0bf    = (u16*)x0f;
    u16* mm      = (u16*)bufA;
    u16* hbuf    = (u16*)bufB;
    int* p_local = (int*)bufA;   // dead before first conv gemm writes mm

    hipMemsetAsync(pooled, 0, (size_t)NG * 256 * sizeof(float), stream);

    wt_prep<<<NADJ * NLAY, 256, 0, stream>>>(conv_w, wt);

    // x0 = bf16(relu(x @ lin0_w + lin0_b))
    gemm_nk128<<<NN / 32, 256, 0, stream>>>(x, lin0_w, nullptr, x0bf, lin0_b,
                                            nullptr, 1);

    for (int a = 0; a < NADJ; ++a) {
        const int* row = ei + (size_t)a * 2 * NE;
        const int* col = row + NE;

        hipMemsetAsync(cnt, 0, NN * sizeof(int), stream);
        hist_plocal<<<(NE + 255) / 256, 256, 0, stream>>>(col, cnt, p_local);
        block_sums<<<SCAN_BLOCKS, 256, 0, stream>>>(cnt, bsum);
        scan_bsums<<<1, 512, 0, stream>>>(bsum);
        write_rowptr<<<SCAN_BLOCKS, 256, 0, stream>>>(cnt, bsum, row_ptr, dis);
        scatter_edges<<<(NE + 255) / 256, 256, 0, stream>>>(row, col, p_local,
                                                            row_ptr, csr_src);

        const u16* h = x0bf;
        for (int l = 0; l < NLAY; ++l) {
            const u16* Wt = wt + ((size_t)a * NLAY + l) * HD * HD;
            gemm_mfma_conv<<<(NN + 127) / 128, 256, 0, stream>>>(h, Wt, mm, dis);
            agg_relu<<<(NN + 3) / 4, 256, 0, stream>>>(mm, row_ptr, csr_src,
                                                       dis, hbuf);
            h = hbuf;
        }
        pool_add<<<(NN + 63) / 64, 128, 0, stream>>>(hbuf, batch, pooled, a * HD);
    }

    head<<<NG, 128, 0, stream>>>(pooled, lin1_w, lin1_b, lin2_w, lin2_b, out);
}

// Round 7
// 810.615 us; speedup vs baseline: 2.1318x; 1.0331x over previous
//
#include <hip/hip_runtime.h>

#define NN 100000
#define NE 1600000
#define NADJ 2
#define NLAY 3
#define HD 128
#define NG 1024

#define SCAN_BLOCKS ((NN + 255) / 256)   // 391

typedef unsigned int uint32;
typedef unsigned short u16;

typedef __attribute__((ext_vector_type(8))) short bfrag8;   // 8 bf16 (4 VGPR)
typedef __attribute__((ext_vector_type(4))) float f32x4;

__device__ __forceinline__ u16 f2bf(float f) {   // RNE pack
    uint32 u = __float_as_uint(f);
    u += 0x7FFFu + ((u >> 16) & 1u);
    return (u16)(u >> 16);
}
__device__ __forceinline__ float bflo(uint32 u) { return __uint_as_float(u << 16); }
__device__ __forceinline__ float bfhi(uint32 u) { return __uint_as_float(u & 0xFFFF0000u); }

// x (fp32) -> bf16, 8 elems/thread
__global__ __launch_bounds__(256) void to_bf16(const float* __restrict__ in,
                                               u16* __restrict__ o) {
    int i = blockIdx.x * 256 + threadIdx.x;          // grid covers NN*HD/8 exactly
    float4 a = ((const float4*)in)[i * 2];
    float4 b = ((const float4*)in)[i * 2 + 1];
    uint4 v;
    v.x = (uint32)f2bf(a.x) | ((uint32)f2bf(a.y) << 16);
    v.y = (uint32)f2bf(a.z) | ((uint32)f2bf(a.w) << 16);
    v.z = (uint32)f2bf(b.x) | ((uint32)f2bf(b.y) << 16);
    v.w = (uint32)f2bf(b.z) | ((uint32)f2bf(b.w) << 16);
    ((uint4*)o)[i] = v;
}

// one-time: wt[b][n][k] = bf16(W_b[k][n]); b in [0,6) -> conv, b==6 -> lin0_w
__global__ void wt_prep(const float* __restrict__ conv_w,
                        const float* __restrict__ lin0_w, u16* __restrict__ wt) {
    const float* W = (blockIdx.x < 6) ? conv_w + (size_t)blockIdx.x * HD * HD
                                      : lin0_w;
    u16* o = wt + (size_t)blockIdx.x * HD * HD;
    for (int i = 0; i < 64; ++i) {
        int idx = i * 256 + threadIdx.x;
        int n = idx >> 7, k = idx & 127;
        o[idx] = f2bf(W[k * 128 + n]);
    }
}

// ---------------- MFMA GEMM: out = bf16( post( A @ W ) ) --------------------
// A bf16 [NN][128], Wt bf16 [n][k]. 128 rows/block, 4 waves (2x2), K=128.
// post: optional *dis[row], +bias[col], relu.
// LDS 16B slots XOR-swizzled: slot ^= row&15 (T2; <=2-way conflicts = free).
__global__ __launch_bounds__(256) void gemm_mfma(
    const u16* __restrict__ Abf, const u16* __restrict__ Wt,
    u16* __restrict__ outbf, const float* __restrict__ dis,
    const float* __restrict__ bias, int relu)
{
    __shared__ u16 sA[128 * 128];
    __shared__ u16 sB[128 * 128];
    const int t = threadIdx.x;
    const int row0 = blockIdx.x * 128;

    #pragma unroll
    for (int i = 0; i < 8; ++i) {
        int f = i * 256 + t;                  // 16B-slot id: row=f>>4, s=f&15
        int r = f >> 4, s = f & 15;
        int gr = min(row0 + r, NN - 1);       // tail clamp
        uint4 v = ((const uint4*)Abf)[(size_t)gr * 16 + s];
        *(uint4*)&sA[(r * 16 + (s ^ (r & 15))) * 8] = v;
    }
    #pragma unroll
    for (int i = 0; i < 8; ++i) {
        int f = i * 256 + t;
        int r = f >> 4, s = f & 15;
        uint4 v = ((const uint4*)Wt)[f];
        *(uint4*)&sB[(r * 16 + (s ^ (r & 15))) * 8] = v;
    }
    __syncthreads();

    const int w = t >> 6, lane = t & 63;
    const int wr = (w >> 1) * 64, wc = (w & 1) * 64;
    const int lr = lane & 15, kg = lane >> 4;

    const f32x4 z = {0.f, 0.f, 0.f, 0.f};
    f32x4 acc[4][4];
    #pragma unroll
    for (int i = 0; i < 4; ++i)
        #pragma unroll
        for (int j = 0; j < 4; ++j) acc[i][j] = z;

    #pragma unroll
    for (int ks = 0; ks < 4; ++ks) {          // K = 4 x 32
        bfrag8 a[4], b[4];
        #pragma unroll
        for (int i = 0; i < 4; ++i) {
            int r = wr + i * 16 + lr;
            int s = (ks * 4 + kg) ^ (r & 15);
            a[i] = *(const bfrag8*)&sA[(r * 16 + s) * 8];
        }
        #pragma unroll
        for (int j = 0; j < 4; ++j) {
            int r = wc + j * 16 + lr;
            int s = (ks * 4 + kg) ^ (r & 15);
            b[j] = *(const bfrag8*)&sB[(r * 16 + s) * 8];
        }
        #pragma unroll
        for (int i = 0; i < 4; ++i)
            #pragma unroll
            for (int j = 0; j < 4; ++j)
                acc[i][j] = __builtin_amdgcn_mfma_f32_16x16x32_bf16(
                    a[i], b[j], acc[i][j], 0, 0, 0);
    }

    // C/D: col = lane&15, row = (lane>>4)*4 + reg   [m89-verified]
    #pragma unroll
    for (int i = 0; i < 4; ++i) {
        #pragma unroll
        for (int r = 0; r < 4; ++r) {
            int grow = row0 + wr + i * 16 + kg * 4 + r;
            if (grow < NN) {
                float ds = dis ? dis[grow] : 1.f;
                #pragma unroll
                for (int j = 0; j < 4; ++j) {
                    int gcol = wc + j * 16 + lr;
                    float o = acc[i][j][r] * ds;
                    if (bias) o += bias[gcol];
                    if (relu) o = fmaxf(o, 0.f);
                    outbf[(size_t)grow * 128 + gcol] = f2bf(o);
                }
            }
        }
    }
}

// histogram of col + per-edge local offset (old count), coalesced write
__global__ void hist_plocal(const int* __restrict__ col,
                            int* __restrict__ cnt, int* __restrict__ p_local) {
    int e = blockIdx.x * 256 + threadIdx.x;
    if (e < NE) p_local[e] = atomicAdd(&cnt[col[e]], 1);
}

// ---- hierarchical scan: cnt -> row_ptr (exclusive), dis = rsqrt(cnt+1)

__global__ __launch_bounds__(256) void block_sums(
    const int* __restrict__ cnt, int* __restrict__ bsum)
{
    __shared__ int ws[4];
    int i = blockIdx.x * 256 + threadIdx.x;
    int v = (i < NN) ? cnt[i] : 0;
    #pragma unroll
    for (int off = 32; off > 0; off >>= 1) v += __shfl_xor(v, off);
    int wid = threadIdx.x >> 6;
    if ((threadIdx.x & 63) == 0) ws[wid] = v;
    __syncthreads();
    if (threadIdx.x == 0) bsum[blockIdx.x] = ws[0] + ws[1] + ws[2] + ws[3];
}

__global__ __launch_bounds__(512) void scan_bsums(int* __restrict__ bsum)
{
    __shared__ int s[512];
    int t = threadIdx.x;
    int v = (t < SCAN_BLOCKS) ? bsum[t] : 0;
    s[t] = v;
    __syncthreads();
    #pragma unroll
    for (int off = 1; off < 512; off <<= 1) {
        int u = (t >= off) ? s[t - off] : 0;
        __syncthreads();
        s[t] += u;
        __syncthreads();
    }
    if (t < SCAN_BLOCKS) bsum[t] = s[t] - v;   // exclusive
}

__global__ __launch_bounds__(256) void write_rowptr(
    const int* __restrict__ cnt, const int* __restrict__ bsum,
    int* __restrict__ row_ptr, float* __restrict__ dis)
{
    __shared__ int s[256];
    int t = threadIdx.x;
    int i = blockIdx.x * 256 + t;
    int v = (i < NN) ? cnt[i] : 0;
    s[t] = v;
    __syncthreads();
    #pragma unroll
    for (int off = 1; off < 256; off <<= 1) {
        int u = (t >= off) ? s[t - off] : 0;
        __syncthreads();
        s[t] += u;
        __syncthreads();
    }
    if (i < NN) {
        int excl = bsum[blockIdx.x] + s[t] - v;
        row_ptr[i] = excl;
        dis[i] = rsqrtf((float)(v + 1));   // +1 self loop
        if (i == NN - 1) row_ptr[NN] = excl + v;
    }
}

// atomic-free scatter: slot = row_ptr[col] + p_local
__global__ void scatter_edges(
    const int* __restrict__ row, const int* __restrict__ col,
    const int* __restrict__ p_local, const int* __restrict__ row_ptr,
    int* __restrict__ csr_src)
{
    int e = blockIdx.x * 256 + threadIdx.x;
    if (e >= NE) return;
    csr_src[row_ptr[col[e]] + p_local[e]] = row[e];
}

// out[i] = bf16( relu( dis[i] * ( mm[i] + sum_e mm[src_e] ) ) ), one wave/node.
__global__ __launch_bounds__(256) void agg_relu(
    const u16* __restrict__ mm, const int* __restrict__ row_ptr,
    const int* __restrict__ csr_src,
    const float* __restrict__ dis, u16* __restrict__ out)
{
    int node = blockIdx.x * 4 + (threadIdx.x >> 6);
    if (node >= NN) return;
    int lane = threadIdx.x & 63;
    const uint32* mv = (const uint32*)mm;
    uint32 self = mv[(size_t)node * 64 + lane];
    float accx = bflo(self);
    float accy = bfhi(self);
    int e0 = row_ptr[node], e1 = row_ptr[node + 1];

    #define UN 16
    int e = e0;
    for (; e + UN <= e1; e += UN) {
        int ss[UN];
        #pragma unroll
        for (int u = 0; u < UN; ++u) ss[u] = csr_src[e + u];
        uint32 vv[UN];
        #pragma unroll
        for (int u = 0; u < UN; ++u)
            vv[u] = mv[(size_t)ss[u] * 64 + lane];
        #pragma unroll
        for (int u = 0; u < UN; ++u) {
            accx += bflo(vv[u]);
            accy += bfhi(vv[u]);
        }
    }
    if (e < e1) {   // masked tail
        int ss[UN];
        float mk[UN];
        #pragma unroll
        for (int u = 0; u < UN; ++u) {
            int idx = e + u;
            ss[u] = csr_src[min(idx, e1 - 1)];
            mk[u] = (idx < e1) ? 1.f : 0.f;
        }
        uint32 vv[UN];
        #pragma unroll
        for (int u = 0; u < UN; ++u)
            vv[u] = mv[(size_t)ss[u] * 64 + lane];
        #pragma unroll
        for (int u = 0; u < UN; ++u) {
            accx = fmaf(mk[u], bflo(vv[u]), accx);
            accy = fmaf(mk[u], bfhi(vv[u]), accy);
        }
    }
    #undef UN

    float d = dis[node];
    uint32 po = (uint32)f2bf(fmaxf(d * accx, 0.f))
              | ((uint32)f2bf(fmaxf(d * accy, 0.f)) << 16);
    ((uint32*)out)[(size_t)node * 64 + lane] = po;
}

// pooled[batch[n]][aoff + c] += h[n][c]   (h bf16, sorted batch)
__global__ __launch_bounds__(128) void pool_add(
    const u16* __restrict__ h, const int* __restrict__ batch,
    float* __restrict__ pooled, int aoff)
{
    int c = threadIdx.x;
    int n0 = blockIdx.x * 64;
    int nend = min(n0 + 64, NN);
    int cur = batch[n0];
    float acc = 0.f;
    for (int n = n0; n < nend; ++n) {
        int g = batch[n];
        if (g != cur) {
            atomicAdd(&pooled[(size_t)cur * 256 + aoff + c], acc);
            acc = 0.f;
            cur = g;
        }
        acc += __uint_as_float((uint32)h[(size_t)n * 128 + c] << 16);
    }
    atomicAdd(&pooled[(size_t)cur * 256 + aoff + c], acc);
}

// out[g] = relu(pooled[g] @ w1 + b1) @ w2 + b2
__global__ __launch_bounds__(128) void head(
    const float* __restrict__ pooled,
    const float* __restrict__ w1, const float* __restrict__ b1,
    const float* __restrict__ w2, const float* __restrict__ b2,
    float* __restrict__ out)
{
    __shared__ float sp[256];
    __shared__ float sg[128];
    int g = blockIdx.x, t = threadIdx.x;
    sp[t] = pooled[(size_t)g * 256 + t];
    sp[t + 128] = pooled[(size_t)g * 256 + 128 + t];
    __syncthreads();
    float acc = b1[t];
    #pragma unroll 8
    for (int k = 0; k < 256; ++k) acc = fmaf(sp[k], w1[k * 128 + t], acc);
    sg[t] = fmaxf(acc, 0.f) * w2[t];
    __syncthreads();
    for (int s2 = 64; s2 > 0; s2 >>= 1) {
        if (t < s2) sg[t] += sg[t + s2];
        __syncthreads();
    }
    if (t == 0) out[g] = sg[0] + b2[0];
}

extern "C" void kernel_launch(void* const* d_in, const int* in_sizes, int n_in,
                              void* d_out, int out_size, void* d_ws, size_t ws_size,
                              hipStream_t stream) {
    const float* x      = (const float*)d_in[0];
    const int*   ei     = (const int*)d_in[1];
    const int*   batch  = (const int*)d_in[2];
    const float* lin0_w = (const float*)d_in[3];
    const float* lin0_b = (const float*)d_in[4];
    const float* conv_w = (const float*)d_in[5];
    const float* lin1_w = (const float*)d_in[6];
    const float* lin1_b = (const float*)d_in[7];
    const float* lin2_w = (const float*)d_in[8];
    const float* lin2_b = (const float*)d_in[9];
    float* out = (float*)d_out;

    const size_t NB = (size_t)NN * HD;
    float* x0f    = (float*)d_ws;              // first half: x0 bf16; second: xbf
    float* bufA   = x0f + NB;                  // mm (bf16); also p_local
    float* bufB   = bufA + NB;                 // h (bf16)
    float* pooled = bufB + NB;
    int*   cnt     = (int*)(pooled + (size_t)NG * 256);
    int*   row_ptr = cnt + NN;
    float* dis     = (float*)(row_ptr + NN + 1);
    int*   csr_src = (int*)(dis + NN);
    int*   bsum    = csr_src + NE;
    u16*   wt      = (u16*)(bsum + 512);       // 7 x 128 x 128 bf16 = 224 KB

    u16* x0bf    = (u16*)x0f;                  // NB bf16 = 25.6 MB
    u16* xbf     = (u16*)(x0f + NB / 2);       // x as bf16, 25.6 MB
    u16* mm      = (u16*)bufA;
    u16* hbuf    = (u16*)bufB;
    int* p_local = (int*)bufA;   // dead before first conv gemm writes mm

    hipMemsetAsync(pooled, 0, (size_t)NG * 256 * sizeof(float), stream);

    to_bf16<<<(NN * HD / 8) / 256 + 1, 256, 0, stream>>>(x, xbf);
    wt_prep<<<NADJ * NLAY + 1, 256, 0, stream>>>(conv_w, lin0_w, wt);

    // x0 = bf16(relu(x @ lin0_w + lin0_b))   via MFMA
    gemm_mfma<<<(NN + 127) / 128, 256, 0, stream>>>(
        xbf, wt + 6 * HD * HD, x0bf, nullptr, lin0_b, 1);

    for (int a = 0; a < NADJ; ++a) {
        const int* row = ei + (size_t)a * 2 * NE;
        const int* col = row + NE;

        hipMemsetAsync(cnt, 0, NN * sizeof(int), stream);
        hist_plocal<<<(NE + 255) / 256, 256, 0, stream>>>(col, cnt, p_local);
        block_sums<<<SCAN_BLOCKS, 256, 0, stream>>>(cnt, bsum);
        scan_bsums<<<1, 512, 0, stream>>>(bsum);
        write_rowptr<<<SCAN_BLOCKS, 256, 0, stream>>>(cnt, bsum, row_ptr, dis);
        scatter_edges<<<(NE + 255) / 256, 256, 0, stream>>>(row, col, p_local,
                                                            row_ptr, csr_src);

        const u16* h = x0bf;
        for (int l = 0; l < NLAY; ++l) {
            const u16* Wt = wt + ((size_t)a * NLAY + l) * HD * HD;
            gemm_mfma<<<(NN + 127) / 128, 256, 0, stream>>>(h, Wt, mm, dis,
                                                            nullptr, 0);
            agg_relu<<<(NN + 3) / 4, 256, 0, stream>>>(mm, row_ptr, csr_src,
                                                       dis, hbuf);
            h = hbuf;
        }
        pool_add<<<(NN + 63) / 64, 128, 0, stream>>>(hbuf, batch, pooled, a * HD);
    }

    head<<<NG, 128, 0, stream>>>(pooled, lin1_w, lin1_b, lin2_w, lin2_b, out);
}